// Round 1
// 920.880 us; speedup vs baseline: 1.0803x; 1.0803x over previous
//
#include <hip/hip_runtime.h>

#define NN 2
#define KC 32
#define G  4                    // output channels per wg (one per wave)
#define CG (KC/G)               // 8 channel-groups
#define TT 100
#define HH 64
#define WW 64
#define HWSZ (HH*WW)            // 4096
#define RB 4                    // row-blocks per channel image
#define RROWS 16
#define HALO 14
#define BROWS (RROWS + 2*HALO)  // 44
#define HROWS (2*HALO)          // 28 halo rows staged from neighbor slices
#define SW 65                   // LDS row stride (65%32==1: serial col walks conflict-free)
#define TSZ (BROWS*SW)          // 2860 floats per tile
#define NWG (NN*CG*RB)          // 64
#define FLAG_STRIDE 16          // 64 B per flag slot

typedef float fx4 __attribute__((ext_vector_type(4)));

// coherent (LLC-point) traffic: sc0 sc1 bypasses L1+L2 -> always coherent.
// HARD RULE (R5 lesson): cap concurrent asm loads -- the compiler can't see
// asm outputs as pending loads, so register spills of in-flight values
// silently produce garbage.  Peak here: 7 halo + 16 matvec = 23 fx4 in flight
// (was 27 in the 11-chunk version).
#define GLD1(x, p) \
  asm volatile("global_load_dwordx4 %0, %1, off sc0 sc1" : "=&v"(x) : "v"(p) : "memory")
#define GLD8(x0,x1,x2,x3,x4,x5,x6,x7,p0,p1,p2,p3,p4,p5,p6,p7) \
  asm volatile( \
    "global_load_dwordx4 %0, %8, off sc0 sc1\n\t" \
    "global_load_dwordx4 %1, %9, off sc0 sc1\n\t" \
    "global_load_dwordx4 %2, %10, off sc0 sc1\n\t" \
    "global_load_dwordx4 %3, %11, off sc0 sc1\n\t" \
    "global_load_dwordx4 %4, %12, off sc0 sc1\n\t" \
    "global_load_dwordx4 %5, %13, off sc0 sc1\n\t" \
    "global_load_dwordx4 %6, %14, off sc0 sc1\n\t" \
    "global_load_dwordx4 %7, %15, off sc0 sc1" \
    : "=&v"(x0),"=&v"(x1),"=&v"(x2),"=&v"(x3), \
      "=&v"(x4),"=&v"(x5),"=&v"(x6),"=&v"(x7) \
    : "v"(p0),"v"(p1),"v"(p2),"v"(p3),"v"(p4),"v"(p5),"v"(p6),"v"(p7) \
    : "memory")
#define VWAIT7(x0,x1,x2,x3,x4,x5,x6) \
  asm volatile("s_waitcnt vmcnt(0)" \
    : "+v"(x0),"+v"(x1),"+v"(x2),"+v"(x3),"+v"(x4),"+v"(x5),"+v"(x6) :: "memory")
#define VWAIT8(x0,x1,x2,x3,x4,x5,x6,x7) \
  asm volatile("s_waitcnt vmcnt(0)" \
    : "+v"(x0),"+v"(x1),"+v"(x2),"+v"(x3),"+v"(x4),"+v"(x5),"+v"(x6),"+v"(x7) :: "memory")
#define GST4(p, v) \
  asm volatile("global_store_dwordx4 %0, %1, off sc0 sc1" :: "v"(p), "v"(v) : "memory")

#define BAR_LDS()  asm volatile("s_waitcnt lgkmcnt(0)\n\ts_barrier" ::: "memory")
#define BAR_FULL() asm volatile("s_waitcnt vmcnt(0) lgkmcnt(0)\n\ts_barrier" ::: "memory")
#define LGKM0()    asm volatile("s_waitcnt lgkmcnt(0)" ::: "memory")

// 16-lane inclusive prefix sum via DPP row_shr (DPP row == 16 lanes exactly;
// bound_ctrl=1 -> shifted-out sources read 0, the additive identity).
template<int CTRL>
__device__ __forceinline__ float dpp_shr(float x) {
  return __int_as_float(__builtin_amdgcn_update_dpp(
      0, __float_as_int(x), CTRL, 0xF, 0xF, true));
}
__device__ __forceinline__ float scan16(float s) {
  s += dpp_shr<0x111>(s);   // row_shr:1
  s += dpp_shr<0x112>(s);   // row_shr:2
  s += dpp_shr<0x114>(s);   // row_shr:4
  s += dpp_shr<0x118>(s);   // row_shr:8
  return s;                 // inclusive prefix within each 16-lane group
}

__global__ void __launch_bounds__(256, 1) ring_kernel(
    const float* __restrict__ inbound, const float* __restrict__ Wf,
    const float* __restrict__ bf, const float* __restrict__ Ws,
    const float* __restrict__ bs, float* __restrict__ out,
    unsigned* __restrict__ flags)
{
  __shared__ float T[G*TSZ];    // 4 integral-image tiles, 45.8 KB
  __shared__ fx4   WFS[KC];     // WFS[i][j] = Wf[ch0+j][i]

  const int b    = blockIdx.x;
  const int n    = b >> 5;
  const int cg   = (b >> 2) & (CG-1);
  const int rb   = b & (RB-1);
  const int tid  = threadIdx.x;
  const int lane = tid & 63;
  const int wave = tid >> 6;          // wave w owns tile/channel ch0+w
  const int r0   = rb * RROWS;
  const int ch0  = cg * G;

  const float inh = Ws[0];
  const float exc = Ws[14*29 + 14];
  const float w9  = exc - inh;

  if (tid < KC) {
    fx4 wv;
    wv[0] = Wf[(ch0+0)*KC + tid]; wv[1] = Wf[(ch0+1)*KC + tid];
    wv[2] = Wf[(ch0+2)*KC + tid]; wv[3] = Wf[(ch0+3)*KC + tid];
    WFS[tid] = wv;
  }
  BAR_LDS();

  // thread owns the same spatial fx4 in all 4 channels
  const int off = r0*WW + tid*4;
  const int rl  = tid >> 4;           // own row within block (0..15)
  const int w0  = (tid & 15) * 4;     // own col chunk; (tid&15) == (lane&15)
  const int br  = rl + HALO;

  fx4 base[G];
  #pragma unroll
  for (int j = 0; j < G; ++j) {
    const float* dp = inbound + (size_t)(n*KC + ch0 + j)*HWSZ + off;
    float bsum = bf[ch0+j] + bs[ch0+j];
    base[j][0] = 0.5f*dp[0] + bsum; base[j][1] = 0.5f*dp[1] + bsum;
    base[j][2] = 0.5f*dp[2] + bsum; base[j][3] = 0.5f*dp[3] + bsum;
  }

  // halo staging geometry: 28 halo rows x 16 fx4 = 448 chunks, 7 per lane.
  // Middle 16 rows come from xn registers (no global round trip).
  int  sgofs[7], slofs[7]; bool sval[7];
  #pragma unroll
  for (int q = 0; q < 7; ++q) {
    int id   = lane + 64*q;
    int hrow = id >> 4;                              // 0..27
    int trow = hrow < HALO ? hrow : hrow + RROWS;    // tile rows 0..13, 30..43
    int c4   = (id & 15) * 4;
    int g    = r0 - HALO + trow;
    sval[q]  = (g >= 0 && g < HH);
    int gc   = g < 0 ? 0 : (g > HH-1 ? HH-1 : g);
    sgofs[q] = gc*WW + c4;
    slofs[q] = trow*SW + c4;
  }
  float* Tw = T + wave*TSZ;

  // flags: flag[(n,cg,rb)] == s  <=>  wg finished writing slice s-1.
  const int ownf = ((n<<5) | (cg<<2) | rb) * FLAG_STRIDE;
  int pollf = ownf;
  if (tid < CG)                  pollf = ((n<<5) | (tid<<2) | rb)    * FLAG_STRIDE;
  else if (tid == 8 && rb>0)     pollf = ((n<<5) | (cg<<2) | (rb-1)) * FLAG_STRIDE;
  else if (tid == 9 && rb<RB-1)  pollf = ((n<<5) | (cg<<2) | (rb+1)) * FLAG_STRIDE;
  unsigned* pollp = flags + pollf;
  unsigned* ownp  = flags + ownf;

  fx4 xn[G];                       // persistent state: X[ch0+j][own px]
  #pragma unroll
  for (int j = 0; j < G; ++j) xn[j] = fx4{0.f,0.f,0.f,0.f};

  for (int t = 0; t < TT; ++t) {
    fx4 sf[G], acc[G];
    #pragma unroll
    for (int j = 0; j < G; ++j) { sf[j] = fx4{0,0,0,0}; acc[j] = fx4{0,0,0,0}; }

    if (t > 0) {
      const float* Xprev = out + (size_t)((n*TT + (t-1))*KC)*HWSZ;

      // ---- pre-poll: middle rows of ALL 4 tiles from xn (== X[t-1] here),
      //      row-scanned in registers.  Overlaps the flag wait; safe because
      //      every wave passed last iter's BAR_FULL (tile reads done).
      {
        const int mo = br*SW + w0;
        #pragma unroll
        for (int j = 0; j < G; ++j) {
          fx4 v = xn[j];
          float l0 = v[0], l1 = l0+v[1], l2 = l1+v[2], l3 = l2+v[3];
          float ex = scan16(l3) - l3;               // exclusive row offset
          float* Tr = T + j*TSZ + mo;
          Tr[0]=ex+l0; Tr[1]=ex+l1; Tr[2]=ex+l2; Tr[3]=ex+l3;
        }
      }

      // ---- wait for the 10 producers of slice t-1 ----
      if (tid < 10) {
        const unsigned tgt = (unsigned)t;
        while (__hip_atomic_load(pollp, __ATOMIC_RELAXED, __HIP_MEMORY_SCOPE_AGENT) < tgt) {
          __builtin_amdgcn_s_sleep(1);
        }
      }
      BAR_LDS();   // lgkmcnt(0): commits cross-wave middle writes, then barrier

      fx4 A0,A1,A2,A3,A4,A5,A6,A7, B0,B1,B2,B3,B4,B5,B6,B7;   // <=23 fx4 in flight
      const float* Xp = Xprev + off;

      // ---- stage halo rows (wave w -> channel ch0+w), 7 chunks/lane,
      //      row prefix computed in registers (16-lane group == one row) ----
      {
        const float* Xc = Xprev + (size_t)(ch0 + wave)*HWSZ;
        fx4 h0,h1,h2,h3,h4,h5,h6;
        GLD1(h0,(const fx4*)(Xc+sgofs[0]));  GLD1(h1,(const fx4*)(Xc+sgofs[1]));
        GLD1(h2,(const fx4*)(Xc+sgofs[2]));  GLD1(h3,(const fx4*)(Xc+sgofs[3]));
        GLD1(h4,(const fx4*)(Xc+sgofs[4]));  GLD1(h5,(const fx4*)(Xc+sgofs[5]));
        GLD1(h6,(const fx4*)(Xc+sgofs[6]));
        // batch 1 of matvec rides the same LLC round trip
        GLD8(A0,A1,A2,A3,A4,A5,A6,A7,
          (const fx4*)(Xp+(size_t)0*HWSZ),(const fx4*)(Xp+(size_t)1*HWSZ),
          (const fx4*)(Xp+(size_t)2*HWSZ),(const fx4*)(Xp+(size_t)3*HWSZ),
          (const fx4*)(Xp+(size_t)4*HWSZ),(const fx4*)(Xp+(size_t)5*HWSZ),
          (const fx4*)(Xp+(size_t)6*HWSZ),(const fx4*)(Xp+(size_t)7*HWSZ));
        GLD8(B0,B1,B2,B3,B4,B5,B6,B7,
          (const fx4*)(Xp+(size_t)8*HWSZ),(const fx4*)(Xp+(size_t)9*HWSZ),
          (const fx4*)(Xp+(size_t)10*HWSZ),(const fx4*)(Xp+(size_t)11*HWSZ),
          (const fx4*)(Xp+(size_t)12*HWSZ),(const fx4*)(Xp+(size_t)13*HWSZ),
          (const fx4*)(Xp+(size_t)14*HWSZ),(const fx4*)(Xp+(size_t)15*HWSZ));
        VWAIT7(h0,h1,h2,h3,h4,h5,h6);   // vmcnt(0): drains A,B too (concurrent)
        fx4 hh[7] = {h0,h1,h2,h3,h4,h5,h6};
        #pragma unroll
        for (int q = 0; q < 7; ++q) {
          fx4 v = sval[q] ? hh[q] : fx4{0.f,0.f,0.f,0.f};
          float l0 = v[0], l1 = l0+v[1], l2 = l1+v[2], l3 = l2+v[3];
          float ex = scan16(l3) - l3;
          float* Tr = Tw + slofs[q];
          Tr[0]=ex+l0; Tr[1]=ex+l1; Tr[2]=ex+l2; Tr[3]=ex+l3;
        }
      }

      // ---- column scan on own tile (rows already row-scanned) ----
      LGKM0();                        // own-wave halo writes visible
      {
        float* Tc = Tw + lane;
        float a = 0.f;
        #pragma unroll 4
        for (int r = 0; r < BROWS; ++r) { a += Tc[r*SW]; Tc[r*SW] = a; }
      }
      BAR_LDS();                      // all 4 tiles ready for cross-wave reads

      // ---- box fields: own 4 px in each of the 4 tiles ----
      #pragma unroll
      for (int j = 0; j < G; ++j) {
        const float* Tj = T + j*TSZ;
        #pragma unroll
        for (int jj = 0; jj < 4; ++jj) {
          int w = w0 + jj;
          int hi  = br + 14, lo  = br - 15;
          int whi = (w + 14 > 63) ? 63 : (w + 14);
          int wlo = w - 15;
          float b29 = Tj[hi*SW + whi];
          if (wlo >= 0) b29 -= Tj[hi*SW + wlo];
          if (lo  >= 0) { b29 -= Tj[lo*SW + whi]; if (wlo >= 0) b29 += Tj[lo*SW + wlo]; }
          int hi2  = br + 4, lo2 = br - 5;
          int whi2 = (w + 4 > 63) ? 63 : (w + 4);
          int wlo2 = w - 5;
          float b9 = Tj[hi2*SW + whi2];
          if (wlo2 >= 0) b9 -= Tj[hi2*SW + wlo2];
          b9 -= Tj[lo2*SW + whi2];
          if (wlo2 >= 0) b9 += Tj[lo2*SW + wlo2];
          sf[j][jj] = inh*b29 + w9*b9;
        }
      }

      // ---- matvec: two batches of 16 channels, registers reused ----
      #define ACC4(V, i) do { fx4 wv = WFS[i]; \
        acc[0] += wv[0]*(V); acc[1] += wv[1]*(V); \
        acc[2] += wv[2]*(V); acc[3] += wv[3]*(V); } while (0)
      VWAIT8(A0,A1,A2,A3,A4,A5,A6,A7);
      VWAIT8(B0,B1,B2,B3,B4,B5,B6,B7);
      ACC4(A0,0);  ACC4(A1,1);  ACC4(A2,2);  ACC4(A3,3);
      ACC4(A4,4);  ACC4(A5,5);  ACC4(A6,6);  ACC4(A7,7);
      GLD8(A0,A1,A2,A3,A4,A5,A6,A7,
        (const fx4*)(Xp+(size_t)16*HWSZ),(const fx4*)(Xp+(size_t)17*HWSZ),
        (const fx4*)(Xp+(size_t)18*HWSZ),(const fx4*)(Xp+(size_t)19*HWSZ),
        (const fx4*)(Xp+(size_t)20*HWSZ),(const fx4*)(Xp+(size_t)21*HWSZ),
        (const fx4*)(Xp+(size_t)22*HWSZ),(const fx4*)(Xp+(size_t)23*HWSZ));
      ACC4(B0,8);  ACC4(B1,9);  ACC4(B2,10); ACC4(B3,11);
      ACC4(B4,12); ACC4(B5,13); ACC4(B6,14); ACC4(B7,15);
      GLD8(B0,B1,B2,B3,B4,B5,B6,B7,
        (const fx4*)(Xp+(size_t)24*HWSZ),(const fx4*)(Xp+(size_t)25*HWSZ),
        (const fx4*)(Xp+(size_t)26*HWSZ),(const fx4*)(Xp+(size_t)27*HWSZ),
        (const fx4*)(Xp+(size_t)28*HWSZ),(const fx4*)(Xp+(size_t)29*HWSZ),
        (const fx4*)(Xp+(size_t)30*HWSZ),(const fx4*)(Xp+(size_t)31*HWSZ));
      VWAIT8(A0,A1,A2,A3,A4,A5,A6,A7);
      VWAIT8(B0,B1,B2,B3,B4,B5,B6,B7);
      ACC4(A0,16); ACC4(A1,17); ACC4(A2,18); ACC4(A3,19);
      ACC4(A4,20); ACC4(A5,21); ACC4(A6,22); ACC4(A7,23);
      ACC4(B0,24); ACC4(B1,25); ACC4(B2,26); ACC4(B3,27);
      ACC4(B4,28); ACC4(B5,29); ACC4(B6,30); ACC4(B7,31);
      #undef ACC4
    }

    // ---- update (xold = xn in registers) + store ----
    float* ob = out + (size_t)((n*TT + t)*KC)*HWSZ + off;
    #pragma unroll
    for (int j = 0; j < G; ++j) {
      fx4 S = base[j] + sf[j] + acc[j];
      fx4 v;
      v[0] = 0.8f*xn[j][0] + 0.2f*fmaxf(S[0], 0.f);
      v[1] = 0.8f*xn[j][1] + 0.2f*fmaxf(S[1], 0.f);
      v[2] = 0.8f*xn[j][2] + 0.2f*fmaxf(S[2], 0.f);
      v[3] = 0.8f*xn[j][3] + 0.2f*fmaxf(S[3], 0.f);
      xn[j] = v;
      GST4((fx4*)(ob + (size_t)(ch0+j)*HWSZ), v);
    }

    // ---- publish slice t ----
    if (t < TT-1) {
      BAR_FULL();
      if (tid == 0) {
        __hip_atomic_store(ownp, (unsigned)(t+1), __ATOMIC_RELAXED,
                           __HIP_MEMORY_SCOPE_AGENT);
      }
    }
  }
}

extern "C" void kernel_launch(void* const* d_in, const int* in_sizes, int n_in,
                              void* d_out, int out_size, void* d_ws, size_t ws_size,
                              hipStream_t stream) {
  const float* inbound = (const float*)d_in[0];
  const float* Wf      = (const float*)d_in[1];
  const float* bf      = (const float*)d_in[2];
  const float* Ws      = (const float*)d_in[3];
  const float* bs      = (const float*)d_in[4];
  float* out = (float*)d_out;
  unsigned* flags = (unsigned*)d_ws;

  hipMemsetAsync(d_ws, 0, NWG*FLAG_STRIDE*sizeof(unsigned), stream);

  void* args[] = {(void*)&inbound, (void*)&Wf, (void*)&bf, (void*)&Ws,
                  (void*)&bs, (void*)&out, (void*)&flags};
  hipLaunchCooperativeKernel((void*)ring_kernel, dim3(NWG), dim3(256),
                             args, 0, stream);
}